// Round 5
// baseline (425.649 us; speedup 1.0000x reference)
//
#include <hip/hip_runtime.h>
#include <hip/hip_bf16.h>
#include <stdint.h>

// Problem dims (fixed by reference setup_inputs)
#define Mdim 8192   // B*S = 4*2048
#define Ndim 4096   // OUT
#define Kdim 4096   // IN

// GEMM tile geometry: 256x256 tile, BK=128 (two K=64 slices), 8 waves.
#define BM 256
#define BN 256
#define BK 128

typedef int v4i __attribute__((ext_vector_type(4)));

__device__ __forceinline__ void gload_lds16(const void* g, void* l) {
  __builtin_amdgcn_global_load_lds(
      (const __attribute__((address_space(1))) unsigned int*)g,
      (__attribute__((address_space(3))) unsigned int*)l,
      16 /*bytes*/, 0 /*offset*/, 0 /*aux*/);
}

// ---------------------------------------------------------------------------
// Kernel 1: quantize activations. xi = clip(rint((x*input_scale)*(1/act)))
// ---------------------------------------------------------------------------
__global__ void quant_x_kernel(const float* __restrict__ x,
                               const float* __restrict__ in_scale,
                               const float* __restrict__ act_scale_p,
                               int8_t* __restrict__ xq) {
  const float inv_act = 1.0f / (*act_scale_p);
  const int64_t tid = (int64_t)blockIdx.x * blockDim.x + threadIdx.x;
  const int64_t base = tid * 16;
  const int k0 = (int)(base & (Kdim - 1));  // Kdim is pow2
  const float4* xv = (const float4*)(x + base);
  const float4* sv = (const float4*)(in_scale + k0);
  alignas(16) int8_t ob[16];
#pragma unroll
  for (int j = 0; j < 4; ++j) {
    float4 xx = xv[j];
    float4 ss = sv[j];
    float r0 = rintf((xx.x * ss.x) * inv_act);
    float r1 = rintf((xx.y * ss.y) * inv_act);
    float r2 = rintf((xx.z * ss.z) * inv_act);
    float r3 = rintf((xx.w * ss.w) * inv_act);
    r0 = fminf(fmaxf(r0, -127.f), 127.f);
    r1 = fminf(fmaxf(r1, -127.f), 127.f);
    r2 = fminf(fmaxf(r2, -127.f), 127.f);
    r3 = fminf(fmaxf(r3, -127.f), 127.f);
    ob[j * 4 + 0] = (int8_t)r0;
    ob[j * 4 + 1] = (int8_t)r1;
    ob[j * 4 + 2] = (int8_t)r2;
    ob[j * 4 + 3] = (int8_t)r3;
  }
  *(v4i*)(xq + base) = *(const v4i*)ob;
}

// ---------------------------------------------------------------------------
// Kernel 2: pack int32 weights to int8 ([N,K] row-major kept as-is = B^T).
// ---------------------------------------------------------------------------
__global__ void pack_w_kernel(const int* __restrict__ w, int8_t* __restrict__ wq) {
  const int64_t tid = (int64_t)blockIdx.x * blockDim.x + threadIdx.x;
  const int64_t base = tid * 16;
  const int4* wv = (const int4*)(w + base);
  alignas(16) int8_t ob[16];
#pragma unroll
  for (int j = 0; j < 4; ++j) {
    int4 t = wv[j];
    ob[j * 4 + 0] = (int8_t)t.x;
    ob[j * 4 + 1] = (int8_t)t.y;
    ob[j * 4 + 2] = (int8_t)t.z;
    ob[j * 4 + 3] = (int8_t)t.w;
  }
  *(v4i*)(wq + base) = *(const v4i*)ob;
}

// ---------------------------------------------------------------------------
// Kernel 3: int8 GEMM, 256^2 8-phase schedule with ONE-PHASE-AHEAD REGISTER
// PIPELINE. C[M,N] = Aq[M,K] . Bq[N,K]^T
//
// R4 post-mortem: phase = LDS-drain + MFMA serialized (1330 cyc) because
// reads(p) feed MFMA(p) and the end barrier waits for the last-serviced
// wave. Fix: MFMA(p) consumes fragments loaded in phase p-1; phase p issues
// reads for p+1 just BEFORE its MFMA cluster, so those reads drain on the
// LDS pipe DURING the ~680-cyc MFMA window. Backend counted lgkmcnt(N)
// skips the just-issued reads naturally (consumed regs are a phase old).
//
// Fragment sets: bf0(ks0 B), bf1(ks1 B), afA/afB (alternating A mh-halves);
// all statically indexed (rule #20). Reads sit AFTER the mid-phase barrier,
// which follows the all-waves VMCNT -> first-read of each ks region is
// still certified (DMA landed in ALL waves' queues) exactly as in R4.
//
// VMCNT placement (queue-traced): entry of p1 and p3, count 6 outstanding
// -> VMCNT(2) drains exactly the 4-load k-slice about to be first-read,
// leaving 2 prefetch loads in flight. Prologue: 8 STG, VMCNT(4), barrier,
// prime bf0/afA. Never vmcnt(0) in the main loop. Swizzle, grid, supertile,
// epilogue unchanged from the 142-us R4 kernel.
// ---------------------------------------------------------------------------
#define PBAR()                        \
  do {                                \
    asm volatile("" ::: "memory");    \
    __builtin_amdgcn_s_barrier();     \
    asm volatile("" ::: "memory");    \
  } while (0)
#define VMCNT(n) asm volatile("s_waitcnt vmcnt(" #n ")" ::: "memory")

// MFMA cluster: acc[mh*4+i][j] += AF[i] * BF[j]
#define MFMA16(mh, AF, BF)                                                \
  do {                                                                    \
    __builtin_amdgcn_s_setprio(1);                                        \
    _Pragma("unroll") for (int i = 0; i < 4; ++i) {                       \
      _Pragma("unroll") for (int j = 0; j < 4; ++j) {                     \
        acc[(mh) * 4 + i][j] = __builtin_amdgcn_mfma_i32_16x16x64_i8(     \
            AF[i], BF[j], acc[(mh) * 4 + i][j], 0, 0, 0);                 \
      }                                                                   \
    }                                                                     \
    __builtin_amdgcn_s_setprio(0);                                        \
  } while (0)

__global__ __launch_bounds__(512, 2) void gemm_i8_kernel(
    const int8_t* __restrict__ Aq, const int8_t* __restrict__ Bq,
    const float* __restrict__ w_scale, const float* __restrict__ bias,
    const float* __restrict__ act_scale_p, float* __restrict__ out) {
  __shared__ alignas(16) int8_t As[2][2][BM * 64];  // [buf][kslice] 4x16KB
  __shared__ alignas(16) int8_t Bs[2][2][BN * 64];

  const int t = threadIdx.x;

  // Grid 512 = 32 m-blocks x 16 n-blocks; 2-wide m supertile for B reuse.
  const int lin = blockIdx.x;
  const int within = lin & 31;
  const int m_blk = (lin >> 5) * 2 + (within & 1);  // 0..31
  const int n_blk = within >> 1;                    // 0..15
  const int m0 = m_blk * BM;
  const int n0 = n_blk * BN;

  // Staging: thread t fills LDS slot t*16 (row = t>>2 in half h, phys chunk
  // = (t&3) ^ ((row>>1)&3) applied to the GLOBAL source address).
  const int srow = t >> 2;                            // 0..127
  const int scol = ((t & 3) ^ ((t >> 3) & 3)) * 16;   // swizzled k-offset
  const int8_t* gA0 = Aq + (int64_t)(m0 + srow) * Kdim + scol;  // rows 0-127
  const int8_t* gA1 = gA0 + (int64_t)128 * Kdim;                // rows 128-255
  const int8_t* gB0 = Bq + (int64_t)(n0 + srow) * Kdim + scol;
  const int8_t* gB1 = gB0 + (int64_t)128 * Kdim;
  const int ldst = t * 16;

  const int w = t >> 6;           // wave 0..7
  const int l = t & 63;           // lane
  const int wm = (w >> 2) * 128;  // wave C-rows origin within tile (2M)
  const int wn = (w & 3) * 64;    // wave C-cols origin within tile (4N)
  const int lrow = l & 15;        // fragment row (m for A, n for B)
  const int lk = ((l >> 4) ^ ((l >> 1) & 3)) * 16;  // swizzled phys chunk
  const int abase = (wm + lrow) * 64 + lk;
  const int bbase = (wn + lrow) * 64 + lk;

  v4i acc[8][4] = {};
  v4i bf0[4], bf1[4], afA[4], afB[4];

#define STG(MAT, buf, ks, h, koff) \
  gload_lds16(g##MAT##h + (koff) + (ks) * 64, &MAT##s[buf][ks][(h) * 8192 + ldst])

  // Prologue: stage tile 0 into buf 0 (ks0's 4 loads FIRST -> oldest).
  STG(A, 0, 0, 0, 0); STG(B, 0, 0, 0, 0);
  STG(A, 0, 0, 1, 0); STG(B, 0, 0, 1, 0);
  STG(A, 0, 1, 0, 0); STG(B, 0, 1, 0, 0);
  STG(A, 0, 1, 1, 0); STG(B, 0, 1, 1, 0);
  VMCNT(4);  // k-slice 0 landed; slice 1's 4 loads stay in flight
  PBAR();
  // Prime phase-0 fragments: bf0 = B(ks0), afA = A(ks0, mh0) from buf 0.
#pragma unroll
  for (int j = 0; j < 4; ++j) bf0[j] = *(const v4i*)&Bs[0][0][bbase + j * 1024];
#pragma unroll
  for (int i = 0; i < 4; ++i) afA[i] = *(const v4i*)&As[0][0][abase + i * 1024];

  for (int kt = 0; kt < Kdim; kt += BK) {
    const int cur = (kt >> 7) & 1;
    const int nxt = cur ^ 1;
    int kn = kt + BK;
    if (kn >= Kdim) kn = 0;  // dummy wrap: keeps vmcnt counts uniform

    // ---- phase 0: MFMA(ks0,mh0) = afA x bf0; load afB = A(ks0,mh1) ----
    STG(A, nxt, 0, 0, kn); STG(B, nxt, 0, 0, kn);   // queue 4 -> 6
    PBAR();
#pragma unroll
    for (int i = 0; i < 4; ++i) afB[i] = *(const v4i*)&As[cur][0][abase + 4096 + i * 1024];
    MFMA16(0, afA, bf0);
    PBAR();

    // ---- phase 1: MFMA(ks0,mh1) = afB x bf0; load bf1,afA from ks1 ----
    VMCNT(2);  // drain this tile's k-slice 1 (oldest 4 of 6); 2 in flight
    STG(A, nxt, 0, 1, kn); STG(B, nxt, 0, 1, kn);   // queue 2 -> 4
    PBAR();    // certifies ks1 across all waves
#pragma unroll
    for (int j = 0; j < 4; ++j) bf1[j] = *(const v4i*)&Bs[cur][1][bbase + j * 1024];
#pragma unroll
    for (int i = 0; i < 4; ++i) afA[i] = *(const v4i*)&As[cur][1][abase + i * 1024];
    MFMA16(1, afB, bf0);
    PBAR();

    // ---- phase 2: MFMA(ks1,mh0) = afA x bf1; load afB = A(ks1,mh1) ----
    STG(A, nxt, 1, 0, kn); STG(B, nxt, 1, 0, kn);   // queue 4 -> 6
    PBAR();
#pragma unroll
    for (int i = 0; i < 4; ++i) afB[i] = *(const v4i*)&As[cur][1][abase + 4096 + i * 1024];
    MFMA16(0, afA, bf1);
    PBAR();

    // ---- phase 3: MFMA(ks1,mh1) = afB x bf1; load bf0,afA from NEXT tile ----
    VMCNT(2);  // drain next tile's k-slice 0 (oldest 4 of 6); 2 in flight
    STG(A, nxt, 1, 1, kn); STG(B, nxt, 1, 1, kn);   // queue 2 -> 4
    PBAR();    // certifies next tile's ks0 across all waves
#pragma unroll
    for (int j = 0; j < 4; ++j) bf0[j] = *(const v4i*)&Bs[nxt][0][bbase + j * 1024];
#pragma unroll
    for (int i = 0; i < 4; ++i) afA[i] = *(const v4i*)&As[nxt][0][abase + i * 1024];
    MFMA16(1, afB, bf1);
    PBAR();
  }
  VMCNT(0);  // drain tail dummy prefetch before exit

  // Epilogue: D mapping col = lane&15, row = (lane>>4)*4 + reg
  const float act = *act_scale_p;
  const int rowbase = (l >> 4) * 4;
#pragma unroll
  for (int j = 0; j < 4; ++j) {
    const int n = n0 + wn + j * 16 + lrow;
    const float sc = act * w_scale[n];
    const float bs = bias[n];
#pragma unroll
    for (int i = 0; i < 8; ++i) {
      const int mb = m0 + wm + i * 16 + rowbase;
#pragma unroll
      for (int r = 0; r < 4; ++r) {
        out[(int64_t)(mb + r) * Ndim + n] = (float)acc[i][j][r] * sc + bs;
      }
    }
  }
}

// ---------------------------------------------------------------------------
extern "C" void kernel_launch(void* const* d_in, const int* in_sizes, int n_in,
                              void* d_out, int out_size, void* d_ws, size_t ws_size,
                              hipStream_t stream) {
  const float* x        = (const float*)d_in[0];
  const float* in_scale = (const float*)d_in[1];
  const float* actp     = (const float*)d_in[2];
  const int*   w_int    = (const int*)d_in[3];
  const float* w_scale  = (const float*)d_in[4];
  const float* bias     = (const float*)d_in[5];
  float* out = (float*)d_out;

  int8_t* Aq = (int8_t*)d_ws;                        // 32 MiB
  int8_t* Bq = (int8_t*)d_ws + (size_t)Mdim * Kdim;  // 16 MiB

  {
    const int64_t nthreads = (int64_t)Mdim * Kdim / 16;  // 2,097,152
    quant_x_kernel<<<(int)(nthreads / 256), 256, 0, stream>>>(x, in_scale, actp, Aq);
  }
  {
    const int64_t nthreads = (int64_t)Ndim * Kdim / 16;  // 1,048,576
    pack_w_kernel<<<(int)(nthreads / 256), 256, 0, stream>>>(w_int, Bq);
  }
  {
    gemm_i8_kernel<<<dim3(512), 512, 0, stream>>>(Aq, Bq, w_scale, bias, actp, out);
  }
}

// Round 6
// 407.313 us; speedup vs baseline: 1.0450x; 1.0450x over previous
//
#include <hip/hip_runtime.h>
#include <hip/hip_bf16.h>
#include <stdint.h>

// Problem dims (fixed by reference setup_inputs)
#define Mdim 8192   // B*S = 4*2048
#define Ndim 4096   // OUT
#define Kdim 4096   // IN

// GEMM tile geometry: 256x128 block, 4 waves (2x2 of 128x64), K-slice 64,
// ring-of-3 slice buffers -> 72 KiB LDS -> TWO blocks per CU.
#define BMt 256
#define BNt 128
#define NSLICE (Kdim / 64)   // 64

typedef int v4i __attribute__((ext_vector_type(4)));

__device__ __forceinline__ void gload_lds16(const void* g, void* l) {
  __builtin_amdgcn_global_load_lds(
      (const __attribute__((address_space(1))) unsigned int*)g,
      (__attribute__((address_space(3))) unsigned int*)l,
      16 /*bytes*/, 0 /*offset*/, 0 /*aux*/);
}

// ---------------------------------------------------------------------------
// Kernel 1: quantize activations. xi = clip(rint((x*input_scale)*(1/act)))
// ---------------------------------------------------------------------------
__global__ void quant_x_kernel(const float* __restrict__ x,
                               const float* __restrict__ in_scale,
                               const float* __restrict__ act_scale_p,
                               int8_t* __restrict__ xq) {
  const float inv_act = 1.0f / (*act_scale_p);
  const int64_t tid = (int64_t)blockIdx.x * blockDim.x + threadIdx.x;
  const int64_t base = tid * 16;
  const int k0 = (int)(base & (Kdim - 1));  // Kdim is pow2
  const float4* xv = (const float4*)(x + base);
  const float4* sv = (const float4*)(in_scale + k0);
  alignas(16) int8_t ob[16];
#pragma unroll
  for (int j = 0; j < 4; ++j) {
    float4 xx = xv[j];
    float4 ss = sv[j];
    float r0 = rintf((xx.x * ss.x) * inv_act);
    float r1 = rintf((xx.y * ss.y) * inv_act);
    float r2 = rintf((xx.z * ss.z) * inv_act);
    float r3 = rintf((xx.w * ss.w) * inv_act);
    r0 = fminf(fmaxf(r0, -127.f), 127.f);
    r1 = fminf(fmaxf(r1, -127.f), 127.f);
    r2 = fminf(fmaxf(r2, -127.f), 127.f);
    r3 = fminf(fmaxf(r3, -127.f), 127.f);
    ob[j * 4 + 0] = (int8_t)r0;
    ob[j * 4 + 1] = (int8_t)r1;
    ob[j * 4 + 2] = (int8_t)r2;
    ob[j * 4 + 3] = (int8_t)r3;
  }
  *(v4i*)(xq + base) = *(const v4i*)ob;
}

// ---------------------------------------------------------------------------
// Kernel 2: pack int32 weights to int8 ([N,K] row-major kept as-is = B^T).
// ---------------------------------------------------------------------------
__global__ void pack_w_kernel(const int* __restrict__ w, int8_t* __restrict__ wq) {
  const int64_t tid = (int64_t)blockIdx.x * blockDim.x + threadIdx.x;
  const int64_t base = tid * 16;
  const int4* wv = (const int4*)(w + base);
  alignas(16) int8_t ob[16];
#pragma unroll
  for (int j = 0; j < 4; ++j) {
    int4 t = wv[j];
    ob[j * 4 + 0] = (int8_t)t.x;
    ob[j * 4 + 1] = (int8_t)t.y;
    ob[j * 4 + 2] = (int8_t)t.z;
    ob[j * 4 + 3] = (int8_t)t.w;
  }
  *(v4i*)(wq + base) = *(const v4i*)ob;
}

// ---------------------------------------------------------------------------
// Kernel 3: int8 GEMM. C[M,N] = Aq[M,K] . Bq[N,K]^T
//
// TLP-overlap design (R6): R4's per-phase rhythm measured FULLY SERIALIZED
// (5325 cyc/K-tile = MFMA 2611 + LDS-read 2260 + DMA-write 512) because all
// 8 waves share one barrier domain -> CU alternates LDS-burst / MFMA-burst.
// Three compiler-mediated overlap attempts (R2/R3/R5) failed. This version
// gets overlap from HARDWARE TLP instead: 2 independent blocks per CU
// (separate barrier domains) -> block A's MFMA burst overlaps block B's
// LDS burst on separate pipes, no compiler cooperation needed (m114).
//
// - Block 256x128, 4 waves (2x2 of 128x64): wave tile / acc / fragment
//   layout / epilogue mapping IDENTICAL to the verified R4 kernel.
// - K-slice 64, ring-of-3 buffers: LDS 3x(A 16K + B 8K) = 72 KiB -> 2
//   blocks/CU (144 <= 160 KiB); 8 waves/CU = 2/SIMD (~200 regs/wave OK).
// - Per slice, R4's exact phase form x2: {reads, 3 STG, raw s_barrier,
//   setprio MFMA16, clobbered barrier}; counted VMCNT(6) once per slice
//   (prefetch distance 2: 12 outstanding -> drain next slice's 6; never 0).
// - Certification: slice s readable after end-of-(s-1) VMCNT(6)+PBAR (all
//   waves' DMAs landed). Ring slot (s+2)%3 rewritten only after slice
//   (s-1)'s end barrier, by which point its reads were serviced (compiler
//   waitcnt before consuming MFMAs precedes barrier arrival).
// - Swizzle unchanged (0 conflicts): 64B rows, phys_chunk = logical ^
//   ((row>>1)&3), applied on the GLOBAL source; LDS dest linear.
// ---------------------------------------------------------------------------
#define PBAR()                        \
  do {                                \
    asm volatile("" ::: "memory");    \
    __builtin_amdgcn_s_barrier();     \
    asm volatile("" ::: "memory");    \
  } while (0)
#define VMCNT(n) asm volatile("s_waitcnt vmcnt(" #n ")" ::: "memory")

// MFMA cluster: acc[mh*4+i][j] += AF[i] * BF[j]
#define MFMA16(mh, AF, BF)                                                \
  do {                                                                    \
    __builtin_amdgcn_s_setprio(1);                                        \
    _Pragma("unroll") for (int i = 0; i < 4; ++i) {                       \
      _Pragma("unroll") for (int j = 0; j < 4; ++j) {                     \
        acc[(mh) * 4 + i][j] = __builtin_amdgcn_mfma_i32_16x16x64_i8(     \
            AF[i], BF[j], acc[(mh) * 4 + i][j], 0, 0, 0);                 \
      }                                                                   \
    }                                                                     \
    __builtin_amdgcn_s_setprio(0);                                        \
  } while (0)

__global__ __launch_bounds__(256, 2) void gemm_i8_kernel(
    const int8_t* __restrict__ Aq, const int8_t* __restrict__ Bq,
    const float* __restrict__ w_scale, const float* __restrict__ bias,
    const float* __restrict__ act_scale_p, float* __restrict__ out) {
  __shared__ alignas(16) int8_t As[3][BMt * 64];  // 3 x 16 KiB
  __shared__ alignas(16) int8_t Bs[3][BNt * 64];  // 3 x 8 KiB

  const int t = threadIdx.x;

  // Grid 1024 = 32 m-blocks x 32 n-blocks; 2-wide m supertile for B reuse.
  const int lin = blockIdx.x;
  const int within = lin & 63;
  const int m_blk = (lin >> 6) * 2 + (within & 1);  // 0..31
  const int n_blk = within >> 1;                    // 0..31
  const int m0 = m_blk * BMt;
  const int n0 = n_blk * BNt;

  // Staging (256 thr): thread t fills LDS slot t*16 within each 4KB group
  // (row-in-group = t>>2, phys chunk = (t&3) ^ ((row>>1)&3) applied to the
  // GLOBAL source address; group g = rows g*64..g*64+63, +64 preserves the
  // swizzle phase since (g*64>>1)&3 == 0).
  const int srow = t >> 2;                            // 0..63
  const int scol = ((t & 3) ^ ((t >> 3) & 3)) * 16;   // swizzled k-offset
  const int8_t* gA0 = Aq + (int64_t)(m0 + srow) * Kdim + scol;   // rows 0-63
  const int8_t* gA1 = gA0 + (int64_t)64 * Kdim;                  // 64-127
  const int8_t* gA2 = gA0 + (int64_t)128 * Kdim;                 // 128-191
  const int8_t* gA3 = gA0 + (int64_t)192 * Kdim;                 // 192-255
  const int8_t* gB0 = Bq + (int64_t)(n0 + srow) * Kdim + scol;   // rows 0-63
  const int8_t* gB1 = gB0 + (int64_t)64 * Kdim;                  // 64-127
  const int ldst = t * 16;

  const int w = t >> 6;           // wave 0..3
  const int l = t & 63;           // lane
  const int wm = (w >> 1) * 128;  // wave C-rows origin within tile (2M)
  const int wn = (w & 1) * 64;    // wave C-cols origin within tile (2N)
  const int lrow = l & 15;        // fragment row (m for A, n for B)
  const int lk = ((l >> 4) ^ ((l >> 1) & 3)) * 16;  // swizzled phys chunk
  const int abase = (wm + lrow) * 64 + lk;
  const int bbase = (wn + lrow) * 64 + lk;

  v4i acc[8][4] = {};
  v4i bf[4], afA[4], afB[4];

  // Stage one K=64 slice sp into ring slot rt: A 16KB (4 groups), B 8KB (2).
#define STG_A012(rt, sp)                                    \
  do {                                                      \
    const int ko_ = (sp) * 64;                              \
    gload_lds16(gA0 + ko_, &As[rt][ldst]);                  \
    gload_lds16(gA1 + ko_, &As[rt][4096 + ldst]);           \
    gload_lds16(gA2 + ko_, &As[rt][8192 + ldst]);           \
  } while (0)
#define STG_A3B(rt, sp)                                     \
  do {                                                      \
    const int ko_ = (sp) * 64;                              \
    gload_lds16(gA3 + ko_, &As[rt][12288 + ldst]);          \
    gload_lds16(gB0 + ko_, &Bs[rt][ldst]);                  \
    gload_lds16(gB1 + ko_, &Bs[rt][4096 + ldst]);           \
  } while (0)

  // Prologue: stage slices 0 and 1 (12 loads), wait for slice 0's 6.
  STG_A012(0, 0); STG_A3B(0, 0);
  STG_A012(1, 1); STG_A3B(1, 1);
  VMCNT(6);
  PBAR();

  int ring = 0;  // s % 3
  for (int s = 0; s < NSLICE; ++s) {
    const int r = ring;
    int rt = ring + 2; if (rt >= 3) rt -= 3;        // (s+2) % 3
    int sp = s + 2; if (sp >= NSLICE) sp -= NSLICE; // dummy wrap at tail

    // ---- phase 0: mh=0 ----
#pragma unroll
    for (int j = 0; j < 4; ++j) bf[j] = *(const v4i*)&Bs[r][bbase + j * 1024];
#pragma unroll
    for (int i = 0; i < 4; ++i) afA[i] = *(const v4i*)&As[r][abase + i * 1024];
    STG_A012(rt, sp);
    __builtin_amdgcn_s_barrier();  // raw: backend emits counted lgkm waits
    MFMA16(0, afA, bf);
    PBAR();

    // ---- phase 1: mh=1 ----
#pragma unroll
    for (int i = 0; i < 4; ++i) afB[i] = *(const v4i*)&As[r][abase + 4096 + i * 1024];
    STG_A3B(rt, sp);
    __builtin_amdgcn_s_barrier();
    MFMA16(1, afB, bf);
    VMCNT(6);  // slice s+1's 6 loads landed; s+2's 6 stay in flight
    PBAR();    // certifies slice s+1 across all waves

    ring = ring + 1; if (ring >= 3) ring -= 3;
  }
  VMCNT(0);  // drain tail dummy prefetches

  // Epilogue: D mapping col = lane&15, row = (lane>>4)*4 + reg
  const float act = *act_scale_p;
  const int rowbase = (l >> 4) * 4;
#pragma unroll
  for (int j = 0; j < 4; ++j) {
    const int n = n0 + wn + j * 16 + lrow;
    const float sc = act * w_scale[n];
    const float bs = bias[n];
#pragma unroll
    for (int i = 0; i < 8; ++i) {
      const int mb = m0 + wm + i * 16 + rowbase;
#pragma unroll
      for (int r2 = 0; r2 < 4; ++r2) {
        out[(int64_t)(mb + r2) * Ndim + n] = (float)acc[i][j][r2] * sc + bs;
      }
    }
  }
}

// ---------------------------------------------------------------------------
extern "C" void kernel_launch(void* const* d_in, const int* in_sizes, int n_in,
                              void* d_out, int out_size, void* d_ws, size_t ws_size,
                              hipStream_t stream) {
  const float* x        = (const float*)d_in[0];
  const float* in_scale = (const float*)d_in[1];
  const float* actp     = (const float*)d_in[2];
  const int*   w_int    = (const int*)d_in[3];
  const float* w_scale  = (const float*)d_in[4];
  const float* bias     = (const float*)d_in[5];
  float* out = (float*)d_out;

  int8_t* Aq = (int8_t*)d_ws;                        // 32 MiB
  int8_t* Bq = (int8_t*)d_ws + (size_t)Mdim * Kdim;  // 16 MiB

  {
    const int64_t nthreads = (int64_t)Mdim * Kdim / 16;  // 2,097,152
    quant_x_kernel<<<(int)(nthreads / 256), 256, 0, stream>>>(x, in_scale, actp, Aq);
  }
  {
    const int64_t nthreads = (int64_t)Ndim * Kdim / 16;  // 1,048,576
    pack_w_kernel<<<(int)(nthreads / 256), 256, 0, stream>>>(w_int, Bq);
  }
  {
    gemm_i8_kernel<<<dim3(1024), 256, 0, stream>>>(Aq, Bq, w_scale, bias, actp, out);
  }
}